// Round 2
// baseline (242.113 us; speedup 1.0000x reference)
//
#include <hip/hip_runtime.h>
#include <math.h>

#define CUTOFF    0.3927f
#define TWO_PI_F  6.283185307179586f
#define INV_2PI_F 0.15915494309189535f
#define INV_SQRT2 0.7071067811865476f
#define NB        4
#define NNODE     2048
#define HD        128
#define S_TAB     256
#define SPW       4

__device__ __forceinline__ float sigmoidf_(float x){ return 1.0f/(1.0f+__expf(-x)); }
__device__ __forceinline__ float siluf_(float x){ return x*sigmoidf_(x); }
__device__ __forceinline__ float ssiluf_(float x){ return siluf_(x)*(1.0f/0.6f); }

// ---------------- K1: recover the B=4 distinct globs rows from globs_e ------
__global__ void k_extract_globs(const float* __restrict__ globs_e,
                                const int* __restrict__ src, int ne,
                                float* __restrict__ grows){
    int i = blockIdx.x*blockDim.x + threadIdx.x;   // 4096 threads
    int stride = ne / 4096; if (stride < 1) stride = 1;
    long e = (long)i * stride;
    if (e < ne){
        int b = src[e] / NNODE;                    // src = node + b*NNODE
        const float* g = globs_e + e*16;
        float* dst = grows + b*16;
        #pragma unroll
        for (int j=0;j<16;j++) dst[j] = g[j];      // races write identical values
    }
}

// ---------------- K2: tabulate mij_hat(l, b, rd) at S_TAB sample points -----
// one wave = SPW samples of one (l,b); exact fp32 MLP chain
__device__ __forceinline__ void gemm_stage(float (*buf)[HD], const float* __restrict__ W,
                                           int lane,
                                           const float a0[SPW], const float a1[SPW],
                                           float o0[SPW], float o1[SPW]){
    #pragma unroll
    for (int s=0;s<SPW;s++){ buf[s][lane]=a0[s]; buf[s][lane+64]=a1[s]; }
    __syncthreads();
    #pragma unroll
    for (int s=0;s<SPW;s++){ o0[s]=0.f; o1[s]=0.f; }
    #pragma unroll 4
    for (int k=0;k<HD;k++){
        float w0 = W[k*HD+lane], w1 = W[k*HD+lane+64];
        #pragma unroll
        for (int s=0;s<SPW;s++){ float hk = buf[s][k]; o0[s]+=hk*w0; o1[s]+=hk*w1; }
    }
    __syncthreads();
}

__global__ __launch_bounds__(256)
void k_table(const float* __restrict__ grows, const float* __restrict__ W_e0,
             const float* __restrict__ W_r1, const float* __restrict__ W_r2,
             const float* __restrict__ W_g,  const float* __restrict__ W_v1,
             const float* __restrict__ W_v2, const float* __restrict__ W_vo,
             float* __restrict__ table){
    __shared__ float buf[4][SPW][HD];
    int lane = threadIdx.x & 63, w = threadIdx.x >> 6;
    int chunk = blockIdx.x*4 + w;                 // 0 .. L*NB*(S_TAB/SPW)-1 = 511
    const int CPB = S_TAB / SPW;                  // 64
    int l  = chunk / (NB*CPB);
    int r  = chunk % (NB*CPB);
    int b  = r / CPB;
    int i0 = (r % CPB) * SPW;
    const float step = CUTOFF / (S_TAB - 1);

    const float* We0 = W_e0 + l*17*HD;
    const float* Wr1 = W_r1 + l*HD*HD;
    const float* Wr2 = W_r2 + l*HD*HD;
    const float* Wg  = W_g  + l*HD;
    const float* Wv1 = W_v1 + l*HD*HD;
    const float* Wv2 = W_v2 + l*HD*HD;
    const float* Wvo = W_vo + l*HD;
    float (*bufw)[HD] = buf[w];

    // x = globs[b] @ We0[:16] + rd * We0[16]
    float p0=0.f, p1=0.f;
    #pragma unroll
    for (int k=0;k<16;k++){
        float g = grows[b*16+k];
        p0 += g*We0[k*HD+lane];
        p1 += g*We0[k*HD+lane+64];
    }
    float w160 = We0[16*HD+lane], w161 = We0[16*HD+lane+64];

    float h0[SPW], h1[SPW], t0[SPW], t1[SPW], u0[SPW], u1[SPW];
    #pragma unroll
    for (int s=0;s<SPW;s++){
        float rd = (i0+s)*step;
        h0[s] = siluf_(ssiluf_(p0 + rd*w160));
        h1[s] = siluf_(ssiluf_(p1 + rd*w161));
    }
    // residual(h, Wr1, Wr2)
    gemm_stage(bufw, Wr1, lane, h0,h1, t0,t1);
    #pragma unroll
    for (int s=0;s<SPW;s++){ t0[s]=ssiluf_(t0[s]); t1[s]=ssiluf_(t1[s]); }
    gemm_stage(bufw, Wr2, lane, t0,t1, u0,u1);
    #pragma unroll
    for (int s=0;s<SPW;s++){
        h0[s]=(h0[s]+ssiluf_(u0[s]))*INV_SQRT2;
        h1[s]=(h1[s]+ssiluf_(u1[s]))*INV_SQRT2;
    }
    // m = h * sigmoid(h @ Wg)
    float wg0 = Wg[lane], wg1 = Wg[lane+64];
    #pragma unroll
    for (int s=0;s<SPW;s++){
        float p = h0[s]*wg0 + h1[s]*wg1;
        #pragma unroll
        for (int off=32; off>0; off>>=1) p += __shfl_xor(p, off);
        float g = sigmoidf_(p);
        h0[s]*=g; h1[s]*=g;
    }
    // residual(m, Wv1, Wv2)
    gemm_stage(bufw, Wv1, lane, h0,h1, t0,t1);
    #pragma unroll
    for (int s=0;s<SPW;s++){ t0[s]=ssiluf_(t0[s]); t1[s]=ssiluf_(t1[s]); }
    gemm_stage(bufw, Wv2, lane, t0,t1, u0,u1);
    float wvo0 = Wvo[lane], wvo1 = Wvo[lane+64];
    #pragma unroll
    for (int s=0;s<SPW;s++){
        float v0 = siluf_((h0[s]+ssiluf_(u0[s]))*INV_SQRT2);
        float v1 = siluf_((h1[s]+ssiluf_(u1[s]))*INV_SQRT2);
        float p = v0*wvo0 + v1*wvo1;
        #pragma unroll
        for (int off=32; off>0; off>>=1) p += __shfl_xor(p, off);
        if (lane==0) table[(l*NB+b)*S_TAB + i0 + s] = p;
    }
}

// ---------------- K3: edge stream (both layers), accumulates into dest ------
// dest is pre-initialized with the input coords; atomics add messages on top.
__global__ __launch_bounds__(256)
void k_edges(const float* __restrict__ table_g, const float* __restrict__ rel_coors,
             const float* __restrict__ rel_dists, const int* __restrict__ src,
             const int* __restrict__ tgt, const float* __restrict__ coors_cur,
             const float* __restrict__ scale_p, int layer, int ne,
             float* __restrict__ dest){
    __shared__ float tab[NB*S_TAB];
    for (int i=threadIdx.x; i<NB*S_TAB; i+=blockDim.x)
        tab[i] = table_g[layer*NB*S_TAB + i];
    __syncthreads();

    int e = blockIdx.x*blockDim.x + threadIdx.x;
    if (e >= ne) return;
    int s = src[e], t = tgt[e];
    int b = s / NNODE;

    float rx, ry, rd;
    if (layer == 0){
        float2 rc = ((const float2*)rel_coors)[e];
        rx = rc.x; ry = rc.y;
        rd = rel_dists[e];
    } else {
        float2 ct = ((const float2*)coors_cur)[t];
        float2 cs = ((const float2*)coors_cur)[s];
        rx = ct.x - cs.x; ry = ct.y - cs.y;
        rx -= TWO_PI_F*rintf(rx*INV_2PI_F);     // matches jnp.round (half-even)
        ry -= TWO_PI_F*rintf(ry*INV_2PI_F);
        rd = rx*rx + ry*ry;
    }

    float d = rd * (1.0f/CUTOFF);
    if (d >= 1.0f) return;                       // env == 0 -> zero message
    float d2 = d*d;
    float d5 = d2*d2*d;
    float env = 1.0f + d5*(-21.0f + d*(35.0f + d*(-15.0f)));

    // Catmull-Rom interpolation of mij_hat(rd)
    float u = rd * ((float)(S_TAB-1)/CUTOFF);
    int i1 = (int)u; if (i1 > S_TAB-1) i1 = S_TAB-1;
    float fr = u - (float)i1;
    const float* tb = tab + b*S_TAB;
    int im = i1-1 < 0 ? 0 : i1-1;
    int i2 = i1+1 > S_TAB-1 ? S_TAB-1 : i1+1;
    int i3 = i1+2 > S_TAB-1 ? S_TAB-1 : i1+2;
    float p0=tb[im], p1=tb[i1], p2=tb[i2], p3=tb[i3];
    float mij = p1 + 0.5f*fr*((p2-p0) + fr*((2.f*p0-5.f*p1+4.f*p2-p3)
                               + fr*(3.f*(p1-p2)+p3-p0)));

    float nrm = sqrtf(rx*rx + ry*ry);
    float inv = 1.0f / fmaxf(nrm, 1e-8f);
    float wmul = mij * env * scale_p[layer] * inv;
    float mx = wmul*rx, my = wmul*ry;
    if (mx != 0.f || my != 0.f){
        __hip_atomic_fetch_add(&dest[2*t],   mx, __ATOMIC_RELAXED, __HIP_MEMORY_SCOPE_AGENT);
        __hip_atomic_fetch_add(&dest[2*t+1], my, __ATOMIC_RELAXED, __HIP_MEMORY_SCOPE_AGENT);
    }
}

extern "C" void kernel_launch(void* const* d_in, const int* in_sizes, int n_in,
                              void* d_out, int out_size, void* d_ws, size_t ws_size,
                              hipStream_t stream){
    const float* coors     = (const float*)d_in[0];
    const float* globs_e   = (const float*)d_in[1];
    const float* rel_coors = (const float*)d_in[2];
    const float* rel_dists = (const float*)d_in[3];
    const float* W_e0      = (const float*)d_in[4];
    const float* W_r1      = (const float*)d_in[5];
    const float* W_r2      = (const float*)d_in[6];
    const float* W_g       = (const float*)d_in[7];
    const float* W_v1      = (const float*)d_in[8];
    const float* W_v2      = (const float*)d_in[9];
    const float* W_vo      = (const float*)d_in[10];
    const float* scale     = (const float*)d_in[11];
    const int*   src       = (const int*)d_in[12];
    const int*   tgt       = (const int*)d_in[13];

    int ne  = in_sizes[12];
    int nn2 = in_sizes[0];                     // B*N*2 = 16384

    float* ws     = (float*)d_ws;
    float* grows  = ws;                        // 64
    float* table  = ws + 64;                   // 2*4*S_TAB = 2048
    float* coors1 = table + 2*NB*S_TAB;        // 16384

    size_t cb = (size_t)nn2 * sizeof(float);

    // table build (independent of the copies)
    k_extract_globs<<<16, 256, 0, stream>>>(globs_e, src, ne, grows);
    k_table<<<(2*NB*(S_TAB/SPW))/4, 256, 0, stream>>>(grows, W_e0, W_r1, W_r2,
                                                      W_g, W_v1, W_v2, W_vo, table);
    int eb = (ne + 255)/256;

    // layer 0: coors1 = coors + segment_sum(msg0)
    hipMemcpyAsync(coors1, coors, cb, hipMemcpyDeviceToDevice, stream);
    k_edges<<<eb, 256, 0, stream>>>(table, rel_coors, rel_dists, src, tgt,
                                    nullptr, scale, 0, ne, coors1);

    // layer 1: out = coors1 + segment_sum(msg1) with rel from coors1
    hipMemcpyAsync(d_out, coors1, cb, hipMemcpyDeviceToDevice, stream);
    k_edges<<<eb, 256, 0, stream>>>(table, rel_coors, rel_dists, src, tgt,
                                    coors1, scale, 1, ne, (float*)d_out);
}

// Round 3
// 234.508 us; speedup vs baseline: 1.0324x; 1.0324x over previous
//
#include <hip/hip_runtime.h>
#include <math.h>

#define CUTOFF    0.3927f
#define TWO_PI_F  6.283185307179586f
#define INV_2PI_F 0.15915494309189535f
#define INV_SQRT2 0.7071067811865476f
#define NB        4
#define NNODE     2048
#define HD        128
#define S_TAB     256
#define SG        8          // samples per k_table2 block

__device__ __forceinline__ float sigmoidf_(float x){ return 1.0f/(1.0f+__expf(-x)); }
__device__ __forceinline__ float siluf_(float x){ return x*sigmoidf_(x); }
__device__ __forceinline__ float ssiluf_(float x){ return siluf_(x)*(1.0f/0.6f); }

// ---------------- K1: recover the B=4 distinct globs rows from globs_e ------
__global__ void k_extract_globs(const float* __restrict__ globs_e,
                                const int* __restrict__ src, int ne,
                                float* __restrict__ grows){
    int i = blockIdx.x*blockDim.x + threadIdx.x;   // 4096 threads
    int stride = ne / 4096; if (stride < 1) stride = 1;
    long e = (long)i * stride;
    if (e < ne){
        int b = src[e] >> 11;                      // src = node + b*2048
        const float* g = globs_e + e*16;
        float* dst = grows + b*16;
        #pragma unroll
        for (int j=0;j<16;j++) dst[j] = g[j];      // races write identical values
    }
}

// ---------------- K2: tabulate mij_hat(l,b,rd), GEMM-structured -------------
// 256 blocks: (l, b, sample-group of SG). 256 threads: (sl = sample, j0 = 4 dims).
__device__ __forceinline__ float4 gemv4(const float (*X)[HD+4], int sl,
                                        const float* __restrict__ W, int j0){
    float a0=0.f, a1=0.f, a2=0.f, a3=0.f;
    #pragma unroll 8
    for (int k=0;k<HD;k++){
        float x = X[sl][k];                                  // LDS broadcast
        float4 w = *(const float4*)(W + k*HD + j0);          // coalesced 16B
        a0 += x*w.x; a1 += x*w.y; a2 += x*w.z; a3 += x*w.w;
    }
    return make_float4(a0,a1,a2,a3);
}

__global__ __launch_bounds__(256)
void k_table2(const float* __restrict__ grows, const float* __restrict__ W_e0,
              const float* __restrict__ W_r1, const float* __restrict__ W_r2,
              const float* __restrict__ W_g,  const float* __restrict__ W_v1,
              const float* __restrict__ W_v2, const float* __restrict__ W_vo,
              float* __restrict__ table){
    __shared__ float X[SG][HD+4];
    int tid = threadIdx.x;
    int sl = tid >> 5, jq = tid & 31, j0 = jq*4;
    int blk = blockIdx.x;              // 0..255
    int sg = blk & 31, b = (blk>>5)&3, l = blk>>7;
    const float step = CUTOFF / (S_TAB - 1);
    float rd = (sg*SG + sl)*step;

    const float* We0 = W_e0 + l*17*HD;
    const float* Wr1 = W_r1 + l*HD*HD;
    const float* Wr2 = W_r2 + l*HD*HD;
    const float* Wg  = W_g  + l*HD;
    const float* Wv1 = W_v1 + l*HD*HD;
    const float* Wv2 = W_v2 + l*HD*HD;
    const float* Wvo = W_vo + l*HD;

    // stage 0: h = silu(ssilu([globs(16), rd] @ We0))
    float4 p = make_float4(0,0,0,0);
    #pragma unroll
    for (int k=0;k<16;k++){
        float g = grows[b*16+k];
        float4 w = *(const float4*)(We0 + k*HD + j0);
        p.x += g*w.x; p.y += g*w.y; p.z += g*w.z; p.w += g*w.w;
    }
    float4 w16 = *(const float4*)(We0 + 16*HD + j0);
    float4 h;
    h.x = siluf_(ssiluf_(p.x + rd*w16.x));
    h.y = siluf_(ssiluf_(p.y + rd*w16.y));
    h.z = siluf_(ssiluf_(p.z + rd*w16.z));
    h.w = siluf_(ssiluf_(p.w + rd*w16.w));

    #define STORE4(v) { X[sl][j0]=(v).x; X[sl][j0+1]=(v).y; X[sl][j0+2]=(v).z; X[sl][j0+3]=(v).w; }
    #define SSILU4(v) make_float4(ssiluf_((v).x), ssiluf_((v).y), ssiluf_((v).z), ssiluf_((v).w))

    // residual(h, Wr1, Wr2)
    STORE4(h); __syncthreads();
    float4 t = gemv4(X, sl, Wr1, j0); __syncthreads();
    t = SSILU4(t);
    STORE4(t); __syncthreads();
    float4 u = gemv4(X, sl, Wr2, j0); __syncthreads();
    h.x = (h.x + ssiluf_(u.x))*INV_SQRT2;
    h.y = (h.y + ssiluf_(u.y))*INV_SQRT2;
    h.z = (h.z + ssiluf_(u.z))*INV_SQRT2;
    h.w = (h.w + ssiluf_(u.w))*INV_SQRT2;

    // gate: h *= sigmoid(h @ Wg)
    float4 wg = *(const float4*)(Wg + j0);
    float pg = h.x*wg.x + h.y*wg.y + h.z*wg.z + h.w*wg.w;
    #pragma unroll
    for (int off=16; off>0; off>>=1) pg += __shfl_xor(pg, off);  // 32-lane group
    float gt = sigmoidf_(pg);
    h.x*=gt; h.y*=gt; h.z*=gt; h.w*=gt;

    // residual(m, Wv1, Wv2)
    STORE4(h); __syncthreads();
    t = gemv4(X, sl, Wv1, j0); __syncthreads();
    t = SSILU4(t);
    STORE4(t); __syncthreads();
    u = gemv4(X, sl, Wv2, j0);
    float4 v;
    v.x = siluf_((h.x + ssiluf_(u.x))*INV_SQRT2);
    v.y = siluf_((h.y + ssiluf_(u.y))*INV_SQRT2);
    v.z = siluf_((h.z + ssiluf_(u.z))*INV_SQRT2);
    v.w = siluf_((h.w + ssiluf_(u.w))*INV_SQRT2);
    float4 wvo = *(const float4*)(Wvo + j0);
    float pv = v.x*wvo.x + v.y*wvo.y + v.z*wvo.z + v.w*wvo.w;
    #pragma unroll
    for (int off=16; off>0; off>>=1) pv += __shfl_xor(pv, off);
    if (jq == 0) table[(l*NB+b)*S_TAB + sg*SG + sl] = pv;
}

// ---------------- per-edge message (shared by both edge kernels) ------------
__device__ __forceinline__ bool edge_msg(const float* __restrict__ tab_b,
                                         float rx, float ry, float rd, float sc,
                                         float& mx, float& my){
    float d = rd * (1.0f/CUTOFF);
    if (d >= 1.0f) return false;
    float d2 = d*d;
    float d5 = d2*d2*d;
    float env = 1.0f + d5*(-21.0f + d*(35.0f + d*(-15.0f)));
    float u = rd * ((float)(S_TAB-1)/CUTOFF);
    int i1 = (int)u; if (i1 > S_TAB-1) i1 = S_TAB-1;
    float fr = u - (float)i1;
    int im = i1-1 < 0 ? 0 : i1-1;
    int i2 = i1+1 > S_TAB-1 ? S_TAB-1 : i1+1;
    int i3 = i1+2 > S_TAB-1 ? S_TAB-1 : i1+2;
    float p0=tab_b[im], p1=tab_b[i1], p2=tab_b[i2], p3=tab_b[i3];
    float mij = p1 + 0.5f*fr*((p2-p0) + fr*((2.f*p0-5.f*p1+4.f*p2-p3)
                               + fr*(3.f*(p1-p2)+p3-p0)));
    float nrm = sqrtf(rx*rx + ry*ry);
    float inv = 1.0f / fmaxf(nrm, 1e-8f);
    float wmul = mij * env * sc * inv;
    mx = wmul*rx; my = wmul*ry;
    return true;
}

// ---------------- K3: edge stream -> per-block LDS bins -> partials ---------
__global__ __launch_bounds__(256)
void k_edges_p1(const float* __restrict__ table_g, const float* __restrict__ rel_coors,
                const int* __restrict__ src, const int* __restrict__ tgt,
                const float* __restrict__ coors_cur, const float* __restrict__ scale_p,
                int layer, int ne, int chunk,
                float* __restrict__ partial, int2* __restrict__ header){
    __shared__ float tab[NB*S_TAB];
    __shared__ float bins[2][NNODE*2];
    int tid = threadIdx.x;
    for (int i=tid;i<NB*S_TAB;i+=256) tab[i] = table_g[layer*NB*S_TAB + i];
    for (int i=tid;i<2*NNODE*2;i+=256) ((float*)bins)[i] = 0.f;

    long e0 = (long)blockIdx.x*chunk;
    long e1 = e0 + chunk; if (e1 > ne) e1 = ne;
    int b0 = (e0 < ne) ? (tgt[e0] >> 11) : 0;    // chunk spans <=2 batches
    float sc = scale_p[layer];
    __syncthreads();

    for (long e=e0+tid; e<e1; e+=256){
        int t = tgt[e];
        int b = t >> 11;
        float rx, ry, rd;
        if (layer == 0){
            float2 rc = ((const float2*)rel_coors)[e];
            rx = rc.x; ry = rc.y;
            rd = rx*rx + ry*ry;
        } else {
            int s = src[e];
            float2 ct = ((const float2*)coors_cur)[t];
            float2 cs = ((const float2*)coors_cur)[s];
            rx = ct.x - cs.x; ry = ct.y - cs.y;
            rx -= TWO_PI_F*rintf(rx*INV_2PI_F);   // matches jnp.round
            ry -= TWO_PI_F*rintf(ry*INV_2PI_F);
            rd = rx*rx + ry*ry;
        }
        float mx, my;
        if (edge_msg(tab + b*S_TAB, rx, ry, rd, sc, mx, my)){
            int slot = (b - b0) & 1;
            int loc = (t & (NNODE-1))*2;
            atomicAdd(&bins[slot][loc],   mx);    // ds_add_f32
            atomicAdd(&bins[slot][loc+1], my);
        }
    }
    __syncthreads();

    if (tid == 0){
        int bl = (e1 > e0) ? (tgt[e1-1] >> 11) : -1;
        header[blockIdx.x] = make_int2((e1 > e0) ? b0 : 1, bl);  // x>y means empty
    }
    float* dst = partial + (size_t)blockIdx.x*(2*NNODE*2);
    for (int i=tid;i<2*NNODE*2;i+=256) dst[i] = ((float*)bins)[i];
}

// ---------------- K4: out = base + sum of matching partials -----------------
__global__ __launch_bounds__(256)
void k_reduce(const float* __restrict__ base, const float* __restrict__ partial,
              const int2* __restrict__ header, int nblk, float* __restrict__ out){
    __shared__ int2 hdr[256];
    int tid = threadIdx.x;
    for (int i=tid;i<nblk;i+=256) hdr[i] = header[i];
    __syncthreads();
    int i = blockIdx.x*256 + tid;                // < 16384
    int b = i >> 12, loc = i & (NNODE*2-1);
    float acc = base[i];
    for (int blk=0; blk<nblk; blk++){
        int2 h = hdr[blk];
        if (h.x <= b && b <= h.y)
            acc += partial[(size_t)blk*(2*NNODE*2) + (b - h.x)*(NNODE*2) + loc];
    }
    out[i] = acc;
}

// ---------------- fallback: direct global atomics (round-2 path) ------------
__global__ __launch_bounds__(256)
void k_edges_atomic(const float* __restrict__ table_g, const float* __restrict__ rel_coors,
                    const int* __restrict__ src, const int* __restrict__ tgt,
                    const float* __restrict__ coors_cur, const float* __restrict__ scale_p,
                    int layer, int ne, float* __restrict__ dest){
    __shared__ float tab[NB*S_TAB];
    for (int i=threadIdx.x; i<NB*S_TAB; i+=256) tab[i] = table_g[layer*NB*S_TAB + i];
    __syncthreads();
    int e = blockIdx.x*256 + threadIdx.x;
    if (e >= ne) return;
    int t = tgt[e];
    int b = t >> 11;
    float rx, ry, rd;
    if (layer == 0){
        float2 rc = ((const float2*)rel_coors)[e];
        rx = rc.x; ry = rc.y; rd = rx*rx + ry*ry;
    } else {
        int s = src[e];
        float2 ct = ((const float2*)coors_cur)[t];
        float2 cs = ((const float2*)coors_cur)[s];
        rx = ct.x - cs.x; ry = ct.y - cs.y;
        rx -= TWO_PI_F*rintf(rx*INV_2PI_F);
        ry -= TWO_PI_F*rintf(ry*INV_2PI_F);
        rd = rx*rx + ry*ry;
    }
    float mx, my;
    if (edge_msg(tab + b*S_TAB, rx, ry, rd, scale_p[layer], mx, my)){
        __hip_atomic_fetch_add(&dest[2*t],   mx, __ATOMIC_RELAXED, __HIP_MEMORY_SCOPE_AGENT);
        __hip_atomic_fetch_add(&dest[2*t+1], my, __ATOMIC_RELAXED, __HIP_MEMORY_SCOPE_AGENT);
    }
}

extern "C" void kernel_launch(void* const* d_in, const int* in_sizes, int n_in,
                              void* d_out, int out_size, void* d_ws, size_t ws_size,
                              hipStream_t stream){
    const float* coors     = (const float*)d_in[0];
    const float* globs_e   = (const float*)d_in[1];
    const float* rel_coors = (const float*)d_in[2];
    const float* W_e0      = (const float*)d_in[4];
    const float* W_r1      = (const float*)d_in[5];
    const float* W_r2      = (const float*)d_in[6];
    const float* W_g       = (const float*)d_in[7];
    const float* W_v1      = (const float*)d_in[8];
    const float* W_v2      = (const float*)d_in[9];
    const float* W_vo      = (const float*)d_in[10];
    const float* scale     = (const float*)d_in[11];
    const int*   src       = (const int*)d_in[12];
    const int*   tgt       = (const int*)d_in[13];

    int ne  = in_sizes[12];
    int nn2 = in_sizes[0];                         // 16384

    float* ws     = (float*)d_ws;
    float* grows  = ws;                            // 64 f
    float* table  = ws + 64;                       // 2048 f
    float* coors1 = ws + 64 + 2048;                // 16384 f
    int2*  header = (int2*)(ws + 64 + 2048 + 16384);       // 256 int2 (2KB)
    float* partial= (float*)(header + 256);                // nblk * 32KB
    size_t fixed  = (size_t)(64 + 2048 + 16384)*4 + 256*8;

    // choose partial-block count from available workspace
    int nblk = 0;
    if (ws_size > fixed){
        size_t avail = (ws_size - fixed) / (2*NNODE*2*sizeof(float));
        nblk = (avail > 256) ? 256 : (int)avail;
    }

    k_extract_globs<<<16, 256, 0, stream>>>(globs_e, src, ne, grows);
    k_table2<<<256, 256, 0, stream>>>(grows, W_e0, W_r1, W_r2, W_g, W_v1, W_v2,
                                      W_vo, table);

    if (nblk >= 8){
        int chunk = (ne + nblk - 1)/nblk;
        k_edges_p1<<<nblk, 256, 0, stream>>>(table, rel_coors, src, tgt, nullptr,
                                             scale, 0, ne, chunk, partial, header);
        k_reduce<<<nn2/256, 256, 0, stream>>>(coors, partial, header, nblk, coors1);
        k_edges_p1<<<nblk, 256, 0, stream>>>(table, rel_coors, src, tgt, coors1,
                                             scale, 1, ne, chunk, partial, header);
        k_reduce<<<nn2/256, 256, 0, stream>>>(coors1, partial, header, nblk,
                                              (float*)d_out);
    } else {
        // workspace too small: fall back to global atomics
        size_t cb = (size_t)nn2*sizeof(float);
        int eb = (ne + 255)/256;
        hipMemcpyAsync(coors1, coors, cb, hipMemcpyDeviceToDevice, stream);
        k_edges_atomic<<<eb, 256, 0, stream>>>(table, rel_coors, src, tgt, nullptr,
                                               scale, 0, ne, coors1);
        hipMemcpyAsync(d_out, coors1, cb, hipMemcpyDeviceToDevice, stream);
        k_edges_atomic<<<eb, 256, 0, stream>>>(table, rel_coors, src, tgt, coors1,
                                               scale, 1, ne, (float*)d_out);
    }
}

// Round 4
// 213.613 us; speedup vs baseline: 1.1334x; 1.0978x over previous
//
#include <hip/hip_runtime.h>
#include <math.h>

#define CUTOFF    0.3927f
#define TWO_PI_F  6.283185307179586f
#define INV_2PI_F 0.15915494309189535f
#define INV_SQRT2 0.7071067811865476f
#define NB        4
#define NNODE     2048
#define HD        128
#define S_TAB     256
#define SG        8
#define NBLK      256

__device__ __forceinline__ float sigmoidf_(float x){ return 1.0f/(1.0f+__expf(-x)); }
__device__ __forceinline__ float siluf_(float x){ return x*sigmoidf_(x); }
__device__ __forceinline__ float ssiluf_(float x){ return siluf_(x)*(1.0f/0.6f); }

// ---------------- grid barrier (all NBLK blocks co-resident) ----------------
__device__ __forceinline__ void gbar(int* ctr, int ph, int nblk){
    __syncthreads();
    if (threadIdx.x == 0){
        __builtin_amdgcn_fence(__ATOMIC_RELEASE, "agent");
        __hip_atomic_fetch_add(ctr + ph, 1, __ATOMIC_RELAXED, __HIP_MEMORY_SCOPE_AGENT);
        while (__hip_atomic_load(ctr + ph, __ATOMIC_RELAXED, __HIP_MEMORY_SCOPE_AGENT) < nblk)
            __builtin_amdgcn_s_sleep(8);
        __builtin_amdgcn_fence(__ATOMIC_ACQUIRE, "agent");
    }
    __syncthreads();
}

// ---------------- table build: one block = (l, b, 8 samples) ----------------
struct TabSmem { float X[SG][HD+4]; float g[16]; int probe; };

__device__ __forceinline__ float4 gemv4(const float (*X)[HD+4], int sl,
                                        const float* __restrict__ W, int j0){
    float a0=0.f, a1=0.f, a2=0.f, a3=0.f;
    #pragma unroll 8
    for (int k=0;k<HD;k++){
        float x = X[sl][k];
        float4 w = *(const float4*)(W + k*HD + j0);
        a0 += x*w.x; a1 += x*w.y; a2 += x*w.z; a3 += x*w.w;
    }
    return make_float4(a0,a1,a2,a3);
}

__device__ void table_block(int blk, int tid,
                            const int* __restrict__ src, const float* __restrict__ globs_e,
                            int ne,
                            const float* __restrict__ W_e0, const float* __restrict__ W_r1,
                            const float* __restrict__ W_r2, const float* __restrict__ W_g,
                            const float* __restrict__ W_v1, const float* __restrict__ W_v2,
                            const float* __restrict__ W_vo, float* __restrict__ table,
                            TabSmem& sm){
    int sl = tid >> 5, jq = tid & 31, j0 = jq*4;
    int sg = blk & 31, b = (blk>>5)&3, l = blk>>7;

    // probe an edge of batch b to recover globs[b]
    if (tid == 0) sm.probe = 0x7fffffff;
    __syncthreads();
    int stride = ne >> 8; if (stride < 1) stride = 1;
    int e = tid*stride; if (e >= ne) e = ne-1;
    if ((src[e] >> 11) == b) atomicMin(&sm.probe, e);
    __syncthreads();
    int pe = sm.probe; if (pe == 0x7fffffff) pe = 0;
    if (tid < 16) sm.g[tid] = globs_e[(size_t)pe*16 + tid];
    __syncthreads();

    const float step = CUTOFF / (S_TAB - 1);
    float rd = (sg*SG + sl)*step;

    const float* We0 = W_e0 + l*17*HD;
    const float* Wr1 = W_r1 + l*HD*HD;
    const float* Wr2 = W_r2 + l*HD*HD;
    const float* Wg  = W_g  + l*HD;
    const float* Wv1 = W_v1 + l*HD*HD;
    const float* Wv2 = W_v2 + l*HD*HD;
    const float* Wvo = W_vo + l*HD;

    float4 p = make_float4(0,0,0,0);
    #pragma unroll
    for (int k=0;k<16;k++){
        float g = sm.g[k];
        float4 w = *(const float4*)(We0 + k*HD + j0);
        p.x += g*w.x; p.y += g*w.y; p.z += g*w.z; p.w += g*w.w;
    }
    float4 w16 = *(const float4*)(We0 + 16*HD + j0);
    float4 h;
    h.x = siluf_(ssiluf_(p.x + rd*w16.x));
    h.y = siluf_(ssiluf_(p.y + rd*w16.y));
    h.z = siluf_(ssiluf_(p.z + rd*w16.z));
    h.w = siluf_(ssiluf_(p.w + rd*w16.w));

    #define STORE4(v) { sm.X[sl][j0]=(v).x; sm.X[sl][j0+1]=(v).y; sm.X[sl][j0+2]=(v).z; sm.X[sl][j0+3]=(v).w; }
    #define SSILU4(v) make_float4(ssiluf_((v).x), ssiluf_((v).y), ssiluf_((v).z), ssiluf_((v).w))

    STORE4(h); __syncthreads();
    float4 t = gemv4(sm.X, sl, Wr1, j0); __syncthreads();
    t = SSILU4(t);
    STORE4(t); __syncthreads();
    float4 u = gemv4(sm.X, sl, Wr2, j0); __syncthreads();
    h.x = (h.x + ssiluf_(u.x))*INV_SQRT2;
    h.y = (h.y + ssiluf_(u.y))*INV_SQRT2;
    h.z = (h.z + ssiluf_(u.z))*INV_SQRT2;
    h.w = (h.w + ssiluf_(u.w))*INV_SQRT2;

    float4 wg = *(const float4*)(Wg + j0);
    float pg = h.x*wg.x + h.y*wg.y + h.z*wg.z + h.w*wg.w;
    #pragma unroll
    for (int off=16; off>0; off>>=1) pg += __shfl_xor(pg, off);
    float gt = sigmoidf_(pg);
    h.x*=gt; h.y*=gt; h.z*=gt; h.w*=gt;

    STORE4(h); __syncthreads();
    t = gemv4(sm.X, sl, Wv1, j0); __syncthreads();
    t = SSILU4(t);
    STORE4(t); __syncthreads();
    u = gemv4(sm.X, sl, Wv2, j0);
    float4 v;
    v.x = siluf_((h.x + ssiluf_(u.x))*INV_SQRT2);
    v.y = siluf_((h.y + ssiluf_(u.y))*INV_SQRT2);
    v.z = siluf_((h.z + ssiluf_(u.z))*INV_SQRT2);
    v.w = siluf_((h.w + ssiluf_(u.w))*INV_SQRT2);
    float4 wvo = *(const float4*)(Wvo + j0);
    float pv = v.x*wvo.x + v.y*wvo.y + v.z*wvo.z + v.w*wvo.w;
    #pragma unroll
    for (int off=16; off>0; off>>=1) pv += __shfl_xor(pv, off);
    if (jq == 0) table[(l*NB+b)*S_TAB + sg*SG + sl] = pv;
    #undef STORE4
    #undef SSILU4
}

// ---------------- per-edge message ------------------------------------------
__device__ __forceinline__ bool edge_msg(const float* __restrict__ tab_b,
                                         float rx, float ry, float rd, float sc,
                                         float& mx, float& my){
    float d = rd * (1.0f/CUTOFF);
    if (d >= 1.0f) return false;
    float d2 = d*d;
    float d5 = d2*d2*d;
    float env = 1.0f + d5*(-21.0f + d*(35.0f + d*(-15.0f)));
    float u = rd * ((float)(S_TAB-1)/CUTOFF);
    int i1 = (int)u; if (i1 > S_TAB-1) i1 = S_TAB-1;
    float fr = u - (float)i1;
    int im = i1-1 < 0 ? 0 : i1-1;
    int i2 = i1+1 > S_TAB-1 ? S_TAB-1 : i1+1;
    int i3 = i1+2 > S_TAB-1 ? S_TAB-1 : i1+2;
    float p0=tab_b[im], p1=tab_b[i1], p2=tab_b[i2], p3=tab_b[i3];
    float mij = p1 + 0.5f*fr*((p2-p0) + fr*((2.f*p0-5.f*p1+4.f*p2-p3)
                               + fr*(3.f*(p1-p2)+p3-p0)));
    float nrm = sqrtf(rx*rx + ry*ry);
    float inv = 1.0f / fmaxf(nrm, 1e-8f);
    float wmul = mij * env * sc * inv;
    mx = wmul*rx; my = wmul*ry;
    return true;
}

// ---------------- edge phase: bin chunk into LDS, dump partial --------------
__device__ void edge_phase(int layer, int tid, int blk, int ne, int chunk,
                           const float* __restrict__ rel_coors,
                           const int* __restrict__ src, const int* __restrict__ tgt,
                           const float* __restrict__ coors_cur, float sc,
                           const float* __restrict__ table_g, float* tab,
                           float (*bins)[NNODE*2], float* __restrict__ partial,
                           int2* __restrict__ hdr){
    for (int i=tid;i<NB*S_TAB;i+=256) tab[i] = table_g[layer*NB*S_TAB + i];
    for (int i=tid;i<2*NNODE*2;i+=256) ((float*)bins)[i] = 0.f;
    long e0 = (long)blk*chunk;
    long e1 = e0 + chunk; if (e1 > ne) e1 = ne;
    int b0 = (e0 < ne) ? (tgt[e0] >> 11) : 99;
    __syncthreads();

    for (long e=e0+tid; e<e1; e+=256){
        int t = tgt[e];
        int b = t >> 11;
        float rx, ry;
        if (layer == 0){
            float2 rc = ((const float2*)rel_coors)[e];
            rx = rc.x; ry = rc.y;
        } else {
            int s = src[e];
            float2 ct = ((const float2*)coors_cur)[t];
            float2 cs = ((const float2*)coors_cur)[s];
            rx = ct.x - cs.x; ry = ct.y - cs.y;
            rx -= TWO_PI_F*rintf(rx*INV_2PI_F);
            ry -= TWO_PI_F*rintf(ry*INV_2PI_F);
        }
        float rd = rx*rx + ry*ry;
        float mx, my;
        if (edge_msg(tab + b*S_TAB, rx, ry, rd, sc, mx, my)){
            int slot = (b - b0) & 1;
            int loc = (t & (NNODE-1))*2;
            atomicAdd(&bins[slot][loc],   mx);
            atomicAdd(&bins[slot][loc+1], my);
        }
    }
    __syncthreads();
    if (tid == 0){
        int b1 = (e1 > e0) ? (tgt[e1-1] >> 11) : -1;
        hdr[blk] = make_int2(b0, b1);
    }
    float4* dst = (float4*)(partial + (size_t)blk*(2*NNODE*2));
    const float4* sb = (const float4*)bins;
    for (int i=tid;i<2048;i+=256) dst[i] = sb[i];
}

// ---------------- reduce phase: out = base + sum(matching partials) ---------
__device__ void reduce_phase(int tid, int blk, const float* __restrict__ base,
                             const float* __restrict__ partial,
                             const int2* __restrict__ hdr_g, int2* shdr,
                             float4 (*sred)[16], float* __restrict__ outp){
    shdr[tid] = hdr_g[tid];            // 256 threads, 256 headers
    __syncthreads();
    int fi = tid & 15, pg = tid >> 4;
    int f4i = blk*16 + fi;             // 0..4095
    int b   = f4i >> 10;               // batch (1024 f4 per batch)
    int loc = f4i & 1023;
    float4 acc = make_float4(0,0,0,0);
    #pragma unroll
    for (int k=0;k<16;k++){
        int p = pg*16 + k;
        int2 h = shdr[p];
        bool m = (b >= h.x) & (b <= h.y);
        int s = b - h.x; s = s < 0 ? 0 : (s > 1 ? 1 : s);
        float4 v = *(const float4*)(partial + (size_t)p*(2*NNODE*2) + s*(NNODE*2) + loc*4);
        float mm = m ? 1.f : 0.f;
        acc.x += mm*v.x; acc.y += mm*v.y; acc.z += mm*v.z; acc.w += mm*v.w;
    }
    sred[fi][pg] = acc;
    __syncthreads();
    if (tid < 16){
        float4 a = ((const float4*)base)[blk*16 + tid];
        #pragma unroll
        for (int k=0;k<16;k++){
            float4 v = sred[tid][k];
            a.x += v.x; a.y += v.y; a.z += v.z; a.w += v.w;
        }
        ((float4*)outp)[blk*16 + tid] = a;
    }
}

// ---------------- the persistent mega-kernel --------------------------------
__global__ __launch_bounds__(256)
void k_mega(const float* __restrict__ coors, const float* __restrict__ globs_e,
            const float* __restrict__ rel_coors,
            const float* __restrict__ W_e0, const float* __restrict__ W_r1,
            const float* __restrict__ W_r2, const float* __restrict__ W_g,
            const float* __restrict__ W_v1, const float* __restrict__ W_v2,
            const float* __restrict__ W_vo, const float* __restrict__ scale,
            const int* __restrict__ src, const int* __restrict__ tgt,
            int ne, int chunk, float* __restrict__ table, int2* __restrict__ hdr,
            float* __restrict__ coors1, float* __restrict__ partial,
            int* __restrict__ ctr, float* __restrict__ out){
    __shared__ TabSmem tsm;
    __shared__ float tab[NB*S_TAB];
    __shared__ float bins[2][NNODE*2];
    __shared__ int2 shdr[256];
    __shared__ float4 sred[16][16];
    int tid = threadIdx.x, blk = blockIdx.x;

    table_block(blk, tid, src, globs_e, ne, W_e0, W_r1, W_r2, W_g, W_v1, W_v2,
                W_vo, table, tsm);
    float sc0 = scale[0], sc1 = scale[1];
    gbar(ctr, 0, NBLK);

    edge_phase(0, tid, blk, ne, chunk, rel_coors, src, tgt, nullptr, sc0,
               table, tab, bins, partial, hdr);
    gbar(ctr, 1, NBLK);

    reduce_phase(tid, blk, coors, partial, hdr, shdr, sred, coors1);
    gbar(ctr, 2, NBLK);

    edge_phase(1, tid, blk, ne, chunk, rel_coors, src, tgt, coors1, sc1,
               table, tab, bins, partial, hdr);
    gbar(ctr, 3, NBLK);

    reduce_phase(tid, blk, coors1, partial, hdr, shdr, sred, out);
}

// ---------------- fallback path (small workspace): atomic version -----------
__global__ __launch_bounds__(256)
void k_table_sa(const int* __restrict__ src, const float* __restrict__ globs_e,
                int ne,
                const float* __restrict__ W_e0, const float* __restrict__ W_r1,
                const float* __restrict__ W_r2, const float* __restrict__ W_g,
                const float* __restrict__ W_v1, const float* __restrict__ W_v2,
                const float* __restrict__ W_vo, float* __restrict__ table){
    __shared__ TabSmem tsm;
    table_block(blockIdx.x, threadIdx.x, src, globs_e, ne, W_e0, W_r1, W_r2,
                W_g, W_v1, W_v2, W_vo, table, tsm);
}

__global__ __launch_bounds__(256)
void k_edges_atomic(const float* __restrict__ table_g, const float* __restrict__ rel_coors,
                    const int* __restrict__ src, const int* __restrict__ tgt,
                    const float* __restrict__ coors_cur, const float* __restrict__ scale_p,
                    int layer, int ne, float* __restrict__ dest){
    __shared__ float tab[NB*S_TAB];
    for (int i=threadIdx.x; i<NB*S_TAB; i+=256) tab[i] = table_g[layer*NB*S_TAB + i];
    __syncthreads();
    int e = blockIdx.x*256 + threadIdx.x;
    if (e >= ne) return;
    int t = tgt[e];
    int b = t >> 11;
    float rx, ry;
    if (layer == 0){
        float2 rc = ((const float2*)rel_coors)[e];
        rx = rc.x; ry = rc.y;
    } else {
        int s = src[e];
        float2 ct = ((const float2*)coors_cur)[t];
        float2 cs = ((const float2*)coors_cur)[s];
        rx = ct.x - cs.x; ry = ct.y - cs.y;
        rx -= TWO_PI_F*rintf(rx*INV_2PI_F);
        ry -= TWO_PI_F*rintf(ry*INV_2PI_F);
    }
    float rd = rx*rx + ry*ry;
    float mx, my;
    if (edge_msg(tab + b*S_TAB, rx, ry, rd, scale_p[layer], mx, my)){
        __hip_atomic_fetch_add(&dest[2*t],   mx, __ATOMIC_RELAXED, __HIP_MEMORY_SCOPE_AGENT);
        __hip_atomic_fetch_add(&dest[2*t+1], my, __ATOMIC_RELAXED, __HIP_MEMORY_SCOPE_AGENT);
    }
}

extern "C" void kernel_launch(void* const* d_in, const int* in_sizes, int n_in,
                              void* d_out, int out_size, void* d_ws, size_t ws_size,
                              hipStream_t stream){
    const float* coors     = (const float*)d_in[0];
    const float* globs_e   = (const float*)d_in[1];
    const float* rel_coors = (const float*)d_in[2];
    const float* W_e0      = (const float*)d_in[4];
    const float* W_r1      = (const float*)d_in[5];
    const float* W_r2      = (const float*)d_in[6];
    const float* W_g       = (const float*)d_in[7];
    const float* W_v1      = (const float*)d_in[8];
    const float* W_v2      = (const float*)d_in[9];
    const float* W_vo      = (const float*)d_in[10];
    const float* scale     = (const float*)d_in[11];
    const int*   src       = (const int*)d_in[12];
    const int*   tgt       = (const int*)d_in[13];

    int ne  = in_sizes[12];
    int nn2 = in_sizes[0];                               // 16384

    // ws layout (all 16B-aligned)
    char* w = (char*)d_ws;
    int*   ctr    = (int*)w;                             // 64 B
    float* table  = (float*)(w + 64);                    // 8 KB
    int2*  hdr    = (int2*)(w + 64 + 8192);              // 2 KB
    float* coors1 = (float*)(w + 64 + 8192 + 2048);      // 64 KB
    float* partial= (float*)(w + 64 + 8192 + 2048 + 65536); // 8 MB
    size_t need   = 64 + 8192 + 2048 + 65536 + (size_t)NBLK*(2*NNODE*2)*sizeof(float);

    if (ws_size >= need){
        int chunk = (ne + NBLK - 1)/NBLK;
        hipMemsetAsync(ctr, 0, 64, stream);
        k_mega<<<NBLK, 256, 0, stream>>>(coors, globs_e, rel_coors, W_e0, W_r1,
                                         W_r2, W_g, W_v1, W_v2, W_vo, scale,
                                         src, tgt, ne, chunk, table, hdr,
                                         coors1, partial, ctr, (float*)d_out);
    } else {
        // fallback: direct-atomic path
        size_t cb = (size_t)nn2*sizeof(float);
        int eb = (ne + 255)/256;
        k_table_sa<<<256, 256, 0, stream>>>(src, globs_e, ne, W_e0, W_r1, W_r2,
                                            W_g, W_v1, W_v2, W_vo, table);
        hipMemcpyAsync(coors1, coors, cb, hipMemcpyDeviceToDevice, stream);
        k_edges_atomic<<<eb, 256, 0, stream>>>(table, rel_coors, src, tgt, nullptr,
                                               scale, 0, ne, coors1);
        hipMemcpyAsync(d_out, coors1, cb, hipMemcpyDeviceToDevice, stream);
        k_edges_atomic<<<eb, 256, 0, stream>>>(table, rel_coors, src, tgt, coors1,
                                               scale, 1, ne, (float*)d_out);
    }
}